// Round 1
// baseline (443.379 us; speedup 1.0000x reference)
//
#include <hip/hip_runtime.h>
#include <hip/hip_bf16.h>
#include <cstdint>

// Problem constants (from reference): B=4, T=2048, D=512, FF=2048, E=8, K=2
#define NTOK   8192      // B*T
#define DDIM   512
#define FDIM   2048
#define NEXP   8
#define NSLOT  16384     // 2*NTOK assignments (top-2, always exactly 2 per token)
#define MAXTILES 136     // sum_e ceil(cnt_e/128) <= 16384/128 + 8

typedef __bf16 bf16;
typedef __bf16 bf16x8 __attribute__((ext_vector_type(8)));
typedef float  f32x4  __attribute__((ext_vector_type(4)));

typedef uint32_t __attribute__((address_space(1))) gu32;
typedef uint32_t __attribute__((address_space(3))) lu32;

// async global->LDS, 16B per lane; LDS dest must be wave-uniform base (+lane*16 implicit)
__device__ __forceinline__ void gload16(const void* g, void* l) {
    __builtin_amdgcn_global_load_lds((const gu32*)(uintptr_t)g,
                                     (lu32*)(uintptr_t)l, 16, 0, 0);
}

// ---------------- gating: logits -> softmax -> top2 -> weights; also x->bf16 ----
__global__ __launch_bounds__(256)
void gating_kernel(const float* __restrict__ x, const float* __restrict__ Wg,
                   const float* __restrict__ bg, bf16* __restrict__ xb,
                   int* __restrict__ top_idx, float* __restrict__ top_w,
                   int* __restrict__ counts)
{
    const int w = threadIdx.x >> 6;
    const int l = threadIdx.x & 63;
    const int wid = blockIdx.x * 4 + w;   // 512 blocks * 4 waves = 2048 waves

    // hoist this lane's Wg rows (k = l*8 .. l*8+7) into registers, reused across tokens
    float wreg[8][8];
#pragma unroll
    for (int i = 0; i < 8; ++i) {
        const float4* p = (const float4*)(Wg + (size_t)(l * 8 + i) * NEXP);
        float4 a = p[0], b = p[1];
        wreg[i][0] = a.x; wreg[i][1] = a.y; wreg[i][2] = a.z; wreg[i][3] = a.w;
        wreg[i][4] = b.x; wreg[i][5] = b.y; wreg[i][6] = b.z; wreg[i][7] = b.w;
    }
    float bgv[8];
#pragma unroll
    for (int e = 0; e < 8; ++e) bgv[e] = bg[e];

    for (int n = wid; n < NTOK; n += 2048) {
        const float4* xp = (const float4*)(x + (size_t)n * DDIM + l * 8);
        float4 x0 = xp[0], x1 = xp[1];
        float xf[8] = {x0.x, x0.y, x0.z, x0.w, x1.x, x1.y, x1.z, x1.w};

        bf16x8 xv;
#pragma unroll
        for (int i = 0; i < 8; ++i) xv[i] = (bf16)xf[i];
        *(bf16x8*)(xb + (size_t)n * DDIM + l * 8) = xv;

        float acc[8] = {0.f,0.f,0.f,0.f,0.f,0.f,0.f,0.f};
#pragma unroll
        for (int i = 0; i < 8; ++i)
#pragma unroll
            for (int e = 0; e < 8; ++e)
                acc[e] += xf[i] * wreg[i][e];
#pragma unroll
        for (int m = 32; m >= 1; m >>= 1)
#pragma unroll
            for (int e = 0; e < 8; ++e)
                acc[e] += __shfl_xor(acc[e], m);

        if (l == 0) {
            float logit[8];
#pragma unroll
            for (int e = 0; e < 8; ++e) logit[e] = acc[e] + bgv[e];
            float mx = logit[0];
#pragma unroll
            for (int e = 1; e < 8; ++e) mx = fmaxf(mx, logit[e]);
            float g[8], s = 0.f;
#pragma unroll
            for (int e = 0; e < 8; ++e) { g[e] = expf(logit[e] - mx); s += g[e]; }
            float inv = 1.f / s;
#pragma unroll
            for (int e = 0; e < 8; ++e) g[e] *= inv;
            // top-2, ties -> lower index first (matches lax.top_k)
            int e0 = 0;
#pragma unroll
            for (int e = 1; e < 8; ++e) if (g[e] > g[e0]) e0 = e;
            int e1 = (e0 == 0) ? 1 : 0;
#pragma unroll
            for (int e = 0; e < 8; ++e) if (e != e0 && e != e1 && g[e] > g[e1]) e1 = e;
            float denom = g[e0] + g[e1] + 0.01f;
            top_idx[n * 2 + 0] = e0;
            top_idx[n * 2 + 1] = e1;
            top_w[n * 2 + 0] = g[e0] / denom;
            top_w[n * 2 + 1] = g[e1] / denom;
            atomicAdd(&counts[e0], 1);
            atomicAdd(&counts[e1], 1);
        }
    }
}

// ---------------- scan: offsets, tile map, zero cursors (single thread, tiny) ----
__global__ void scan_kernel(const int* __restrict__ counts, int* __restrict__ offsets,
                            int* __restrict__ tmap_e, int* __restrict__ tmap_rt,
                            int* __restrict__ ntiles, int* __restrict__ cursors)
{
    if (threadIdx.x == 0) {
        int off = 0;
        for (int e = 0; e < NEXP; ++e) { offsets[e] = off; off += counts[e]; cursors[e] = 0; }
        offsets[NEXP] = off;
        int t = 0;
        for (int e = 0; e < NEXP; ++e) {
            int nt = (counts[e] + 127) >> 7;
            for (int rt = 0; rt < nt; ++rt) { tmap_e[t] = e; tmap_rt[t] = rt; ++t; }
        }
        *ntiles = t;
    }
}

// ---------------- scatter: assignment -> slot in per-expert contiguous region ----
__global__ __launch_bounds__(256)
void scatter_kernel(const int* __restrict__ top_idx, const float* __restrict__ top_w,
                    const int* __restrict__ offsets, int* __restrict__ cursors,
                    int* __restrict__ slot_tok, float* __restrict__ slot_w,
                    int* __restrict__ pos)
{
    int n = blockIdx.x * 256 + threadIdx.x;
    if (n >= NTOK) return;
#pragma unroll
    for (int k = 0; k < 2; ++k) {
        int e = top_idx[n * 2 + k];
        int s = offsets[e] + atomicAdd(&cursors[e], 1);
        slot_tok[s] = n;
        slot_w[s] = top_w[n * 2 + k];
        pos[n * 2 + k] = s;
    }
}

// ---------------- fp32 [E][R][C] -> bf16 [E][C][R] transpose+convert ------------
__global__ __launch_bounds__(256)
void transpose_cvt(const float* __restrict__ src, bf16* __restrict__ dst, int R, int C)
{
    __shared__ float tile[32][33];
    const size_t eo = (size_t)blockIdx.z * R * C;
    src += eo; dst += eo;
    int c0 = blockIdx.x * 32, r0 = blockIdx.y * 32;
    int tx = threadIdx.x & 31, ty = threadIdx.x >> 5;   // 32x8
#pragma unroll
    for (int j = 0; j < 4; ++j)
        tile[ty + j * 8][tx] = src[(size_t)(r0 + ty + j * 8) * C + c0 + tx];
    __syncthreads();
#pragma unroll
    for (int j = 0; j < 4; ++j)
        dst[(size_t)(c0 + ty + j * 8) * R + r0 + tx] = (bf16)tile[tx][ty + j * 8];
}

// ---------------- grouped GEMM: C[slot, n] = A[slot, :K] * B_e[n, :K]^T ----------
// FIRST:  A = xb (via slot_tok indirection), B = w1t, Out = Hg (bias+relu+bf16)
// !FIRST: A = Hg (direct slot rows),         B = w2t, Out = Yg (bias, fp32)
template<int KD, int ND, bool FIRST>
__global__ __launch_bounds__(256)
void moe_gemm(const bf16* __restrict__ Adata, const bf16* __restrict__ Bt,
              const float* __restrict__ bias, void* __restrict__ Out,
              const int* __restrict__ slot_tok, const int* __restrict__ offsets,
              const int* __restrict__ tmap_e, const int* __restrict__ tmap_rt,
              const int* __restrict__ ntiles)
{
    const int ty = blockIdx.y;
    if (ty >= *ntiles) return;
    const int e    = tmap_e[ty];
    const int rt   = tmap_rt[ty];
    const int row0 = offsets[e] + rt * 128;
    const int rowEnd = offsets[e + 1];
    const int nb   = blockIdx.x * 128;

    __shared__ __align__(16) bf16 As[128 * 32];
    __shared__ __align__(16) bf16 Bs[128 * 32];

    const int t = threadIdx.x;
    const int w = t >> 6, l = t & 63;
    const int wm = w >> 1, wn = w & 1;

    // staging geometry: 8 chunks of 1KB; wave w stages chunks {2w, 2w+1}
    const int rA0  = (w * 2) * 16 + (l >> 2);
    const int rA1  = (w * 2 + 1) * 16 + (l >> 2);
    const int colb = (l & 3) * 8;

    int srow0 = row0 + rA0; if (srow0 >= NSLOT) srow0 = NSLOT - 1;
    int srow1 = row0 + rA1; if (srow1 >= NSLOT) srow1 = NSLOT - 1;
    const bf16 *aSrc0, *aSrc1;
    if (FIRST) {
        aSrc0 = Adata + (size_t)slot_tok[srow0] * KD + colb;
        aSrc1 = Adata + (size_t)slot_tok[srow1] * KD + colb;
    } else {
        aSrc0 = Adata + (size_t)srow0 * KD + colb;
        aSrc1 = Adata + (size_t)srow1 * KD + colb;
    }
    const bf16* bSrc0 = Bt + ((size_t)e * ND + nb + rA0) * KD + colb;
    const bf16* bSrc1 = Bt + ((size_t)e * ND + nb + rA1) * KD + colb;

    bf16* AsW0 = As + (w * 2) * 512;
    bf16* AsW1 = As + (w * 2 + 1) * 512;
    bf16* BsW0 = Bs + (w * 2) * 512;
    bf16* BsW1 = Bs + (w * 2 + 1) * 512;

    f32x4 acc[4][4] = {};
    const int lr = l & 15;
    const int lk = (l >> 4) * 8;

    for (int k0 = 0; k0 < KD; k0 += 32) {
        gload16(aSrc0 + k0, AsW0);
        gload16(aSrc1 + k0, AsW1);
        gload16(bSrc0 + k0, BsW0);
        gload16(bSrc1 + k0, BsW1);
        __syncthreads();
        bf16x8 aF[4], bF[4];
#pragma unroll
        for (int mi = 0; mi < 4; ++mi)
            aF[mi] = *(const bf16x8*)(As + (wm * 64 + mi * 16 + lr) * 32 + lk);
#pragma unroll
        for (int nj = 0; nj < 4; ++nj)
            bF[nj] = *(const bf16x8*)(Bs + (wn * 64 + nj * 16 + lr) * 32 + lk);
#pragma unroll
        for (int mi = 0; mi < 4; ++mi)
#pragma unroll
            for (int nj = 0; nj < 4; ++nj)
                acc[mi][nj] = __builtin_amdgcn_mfma_f32_16x16x32_bf16(
                    aF[mi], bF[nj], acc[mi][nj], 0, 0, 0);
        __syncthreads();
    }

    const int rowW = row0 + wm * 64;
    const int colW = nb + wn * 64;
#pragma unroll
    for (int mi = 0; mi < 4; ++mi) {
#pragma unroll
        for (int nj = 0; nj < 4; ++nj) {
#pragma unroll
            for (int r = 0; r < 4; ++r) {
                int row = rowW + mi * 16 + (l >> 4) * 4 + r;
                int col = colW + nj * 16 + lr;
                if (row < rowEnd) {
                    float v = acc[mi][nj][r] + bias[e * ND + col];
                    if (FIRST)
                        ((bf16*)Out)[(size_t)row * ND + col] = (bf16)fmaxf(v, 0.f);
                    else
                        ((float*)Out)[(size_t)row * ND + col] = v;
                }
            }
        }
    }
}

// ---------------- combine: out[n] = w0*Y[slot0] + w1*Y[slot1] --------------------
__global__ __launch_bounds__(256)
void combine_kernel(const float* __restrict__ Yg, const int* __restrict__ pos,
                    const float* __restrict__ slot_w, float* __restrict__ out)
{
    int idx = blockIdx.x * 256 + threadIdx.x;  // over NTOK*DDIM/4
    int n = idx >> 7;                           // DDIM/4 = 128
    int d4 = idx & 127;
    int s0 = pos[n * 2 + 0], s1 = pos[n * 2 + 1];
    float w0 = slot_w[s0], w1 = slot_w[s1];
    float4 a = ((const float4*)(Yg + (size_t)s0 * DDIM))[d4];
    float4 b = ((const float4*)(Yg + (size_t)s1 * DDIM))[d4];
    float4 o;
    o.x = w0 * a.x + w1 * b.x;
    o.y = w0 * a.y + w1 * b.y;
    o.z = w0 * a.z + w1 * b.z;
    o.w = w0 * a.w + w1 * b.w;
    ((float4*)out)[idx] = o;
}

extern "C" void kernel_launch(void* const* d_in, const int* in_sizes, int n_in,
                              void* d_out, int out_size, void* d_ws, size_t ws_size,
                              hipStream_t stream)
{
    (void)in_sizes; (void)n_in;
    const float* x  = (const float*)d_in[0];
    const float* Wg = (const float*)d_in[1];
    const float* bg = (const float*)d_in[2];
    const float* W1 = (const float*)d_in[3];
    const float* b1 = (const float*)d_in[4];
    const float* W2 = (const float*)d_in[5];
    const float* b2 = (const float*)d_in[6];
    float* out = (float*)d_out;

    uint8_t* ws = (uint8_t*)d_ws;
    size_t off = 0;
    auto alloc = [&](size_t bytes) -> void* {
        void* p = ws + off;
        off = (off + bytes + 255) & ~(size_t)255;
        return p;
    };
    bf16*  xb      = (bf16*)alloc((size_t)NTOK * DDIM * 2);
    bf16*  w1t     = (bf16*)alloc((size_t)NEXP * FDIM * DDIM * 2);  // [E][FF][D]
    bf16*  w2t     = (bf16*)alloc((size_t)NEXP * DDIM * FDIM * 2);  // [E][D][FF]
    bf16*  Hg      = (bf16*)alloc((size_t)NSLOT * FDIM * 2);
    float* Yg      = (float*)alloc((size_t)NSLOT * DDIM * 4);
    int*   counts  = (int*)alloc(NEXP * 4);
    int*   cursors = (int*)alloc(NEXP * 4);
    int*   offsets = (int*)alloc((NEXP + 1) * 4);
    int*   ntiles  = (int*)alloc(4);
    int*   tmap_e  = (int*)alloc(MAXTILES * 4);
    int*   tmap_rt = (int*)alloc(MAXTILES * 4);
    int*   top_idx = (int*)alloc((size_t)NTOK * 2 * 4);
    float* top_w   = (float*)alloc((size_t)NTOK * 2 * 4);
    int*   pos     = (int*)alloc((size_t)NTOK * 2 * 4);
    int*   slot_tok= (int*)alloc((size_t)NSLOT * 4);
    float* slot_w  = (float*)alloc((size_t)NSLOT * 4);

    if (ws_size < off) {
        // workspace too small: distinguishable failure signature (out = 0)
        hipMemsetAsync(d_out, 0, (size_t)out_size * 4, stream);
        return;
    }

    hipMemsetAsync(counts, 0, NEXP * 4, stream);

    gating_kernel<<<512, 256, 0, stream>>>(x, Wg, bg, xb, top_idx, top_w, counts);
    scan_kernel<<<1, 64, 0, stream>>>(counts, offsets, tmap_e, tmap_rt, ntiles, cursors);
    scatter_kernel<<<(NTOK + 255) / 256, 256, 0, stream>>>(top_idx, top_w, offsets, cursors,
                                                           slot_tok, slot_w, pos);
    transpose_cvt<<<dim3(FDIM / 32, DDIM / 32, NEXP), 256, 0, stream>>>(W1, w1t, DDIM, FDIM);
    transpose_cvt<<<dim3(DDIM / 32, FDIM / 32, NEXP), 256, 0, stream>>>(W2, w2t, FDIM, DDIM);

    moe_gemm<DDIM, FDIM, true><<<dim3(FDIM / 128, MAXTILES), 256, 0, stream>>>(
        xb, w1t, b1, (void*)Hg, slot_tok, offsets, tmap_e, tmap_rt, ntiles);
    moe_gemm<FDIM, DDIM, false><<<dim3(DDIM / 128, MAXTILES), 256, 0, stream>>>(
        Hg, w2t, b2, (void*)Yg, slot_tok, offsets, tmap_e, tmap_rt, ntiles);

    combine_kernel<<<(NTOK * DDIM / 4) / 256, 256, 0, stream>>>(Yg, pos, slot_w, out);
}

// Round 2
// 270.456 us; speedup vs baseline: 1.6394x; 1.6394x over previous
//
#include <hip/hip_runtime.h>
#include <hip/hip_bf16.h>
#include <cstdint>

// Problem constants (from reference): B=4, T=2048, D=512, FF=2048, E=8, K=2
#define NTOK   8192      // B*T
#define DDIM   512
#define FDIM   2048
#define NEXP   8
#define NSLOT  16384     // 2*NTOK assignments (top-2, always exactly 2 per token)
#define MAXTILES 136     // sum_e ceil(cnt_e/128) <= 16384/128 + 8

typedef __bf16 bf16;
typedef __bf16 bf16x8 __attribute__((ext_vector_type(8)));
typedef float  f32x4  __attribute__((ext_vector_type(4)));

typedef uint32_t __attribute__((address_space(1))) gu32;
typedef uint32_t __attribute__((address_space(3))) lu32;

// async global->LDS, 16B per lane; LDS dest must be wave-uniform base (+lane*16 implicit)
__device__ __forceinline__ void gload16(const void* g, void* l) {
    __builtin_amdgcn_global_load_lds((const gu32*)(uintptr_t)g,
                                     (lu32*)(uintptr_t)l, 16, 0, 0);
}

// ---------------- gating: logits -> softmax -> top2 -> weights; also x->bf16 ----
// One wave per token (2 tokens per wave via stride). No register-hoisted Wg:
// Wg is 16KB and L1-resident; per-token re-load is ~2 float4/lane from L1.
__global__ __launch_bounds__(256)
void gating_kernel(const float* __restrict__ x, const float* __restrict__ Wg,
                   const float* __restrict__ bg, bf16* __restrict__ xb,
                   int* __restrict__ top_idx, float* __restrict__ top_w,
                   int* __restrict__ counts)
{
    __shared__ int cnt_s[NEXP];
    if (threadIdx.x < NEXP) cnt_s[threadIdx.x] = 0;
    __syncthreads();

    const int w = threadIdx.x >> 6;
    const int l = threadIdx.x & 63;
    const int gw = blockIdx.x * 4 + w;   // 1024 blocks * 4 waves = 4096 waves

    for (int n = gw; n < NTOK; n += 4096) {
        const float4* xp = (const float4*)(x + (size_t)n * DDIM + l * 8);
        float4 x0 = xp[0], x1 = xp[1];
        float xf[8] = {x0.x, x0.y, x0.z, x0.w, x1.x, x1.y, x1.z, x1.w};

        bf16x8 xv;
#pragma unroll
        for (int i = 0; i < 8; ++i) xv[i] = (bf16)xf[i];
        *(bf16x8*)(xb + (size_t)n * DDIM + l * 8) = xv;

        float acc[8] = {0.f,0.f,0.f,0.f,0.f,0.f,0.f,0.f};
#pragma unroll
        for (int i = 0; i < 8; ++i) {
            const float4* wp = (const float4*)(Wg + (size_t)(l * 8 + i) * NEXP);
            float4 wa = wp[0], wb = wp[1];
            acc[0] += xf[i] * wa.x; acc[1] += xf[i] * wa.y;
            acc[2] += xf[i] * wa.z; acc[3] += xf[i] * wa.w;
            acc[4] += xf[i] * wb.x; acc[5] += xf[i] * wb.y;
            acc[6] += xf[i] * wb.z; acc[7] += xf[i] * wb.w;
        }
#pragma unroll
        for (int m = 32; m >= 1; m >>= 1)
#pragma unroll
            for (int e = 0; e < 8; ++e)
                acc[e] += __shfl_xor(acc[e], m);

        if (l == 0) {
            float logit[8];
#pragma unroll
            for (int e = 0; e < 8; ++e) logit[e] = acc[e] + bg[e];
            float mx = logit[0];
#pragma unroll
            for (int e = 1; e < 8; ++e) mx = fmaxf(mx, logit[e]);
            float g[8], s = 0.f;
#pragma unroll
            for (int e = 0; e < 8; ++e) { g[e] = expf(logit[e] - mx); s += g[e]; }
            float inv = 1.f / s;
#pragma unroll
            for (int e = 0; e < 8; ++e) g[e] *= inv;
            // top-2, ties -> lower index first (matches lax.top_k)
            int e0 = 0;
#pragma unroll
            for (int e = 1; e < 8; ++e) if (g[e] > g[e0]) e0 = e;
            int e1 = (e0 == 0) ? 1 : 0;
#pragma unroll
            for (int e = 0; e < 8; ++e) if (e != e0 && e != e1 && g[e] > g[e1]) e1 = e;
            float denom = g[e0] + g[e1] + 0.01f;
            top_idx[n * 2 + 0] = e0;
            top_idx[n * 2 + 1] = e1;
            top_w[n * 2 + 0] = g[e0] / denom;
            top_w[n * 2 + 1] = g[e1] / denom;
            atomicAdd(&cnt_s[e0], 1);
            atomicAdd(&cnt_s[e1], 1);
        }
    }
    __syncthreads();
    if (threadIdx.x < NEXP) atomicAdd(&counts[threadIdx.x], cnt_s[threadIdx.x]);
}

// ---------------- scan: offsets, tile map, zero cursors (single thread, tiny) ----
__global__ void scan_kernel(const int* __restrict__ counts, int* __restrict__ offsets,
                            int* __restrict__ tmap_e, int* __restrict__ tmap_rt,
                            int* __restrict__ ntiles, int* __restrict__ cursors)
{
    if (threadIdx.x == 0) {
        int off = 0;
        for (int e = 0; e < NEXP; ++e) { offsets[e] = off; off += counts[e]; cursors[e] = 0; }
        offsets[NEXP] = off;
        int t = 0;
        for (int e = 0; e < NEXP; ++e) {
            int nt = (counts[e] + 127) >> 7;
            for (int rt = 0; rt < nt; ++rt) { tmap_e[t] = e; tmap_rt[t] = rt; ++t; }
        }
        *ntiles = t;
    }
}

// ---------------- scatter: assignment -> slot in per-expert contiguous region ----
__global__ __launch_bounds__(256)
void scatter_kernel(const int* __restrict__ top_idx, const float* __restrict__ top_w,
                    const int* __restrict__ offsets, int* __restrict__ cursors,
                    int* __restrict__ slot_tok, float* __restrict__ slot_w,
                    int* __restrict__ pos)
{
    int n = blockIdx.x * 256 + threadIdx.x;
    if (n >= NTOK) return;
#pragma unroll
    for (int k = 0; k < 2; ++k) {
        int e = top_idx[n * 2 + k];
        int s = offsets[e] + atomicAdd(&cursors[e], 1);
        slot_tok[s] = n;
        slot_w[s] = top_w[n * 2 + k];
        pos[n * 2 + k] = s;
    }
}

// ---------------- fp32 [E][R][C] -> bf16 [E][C][R] transpose+convert ------------
__global__ __launch_bounds__(256)
void transpose_cvt(const float* __restrict__ src, bf16* __restrict__ dst, int R, int C)
{
    __shared__ float tile[32][33];
    const size_t eo = (size_t)blockIdx.z * R * C;
    src += eo; dst += eo;
    int c0 = blockIdx.x * 32, r0 = blockIdx.y * 32;
    int tx = threadIdx.x & 31, ty = threadIdx.x >> 5;   // 32x8
#pragma unroll
    for (int j = 0; j < 4; ++j)
        tile[ty + j * 8][tx] = src[(size_t)(r0 + ty + j * 8) * C + c0 + tx];
    __syncthreads();
#pragma unroll
    for (int j = 0; j < 4; ++j)
        dst[(size_t)(c0 + ty + j * 8) * R + r0 + tx] = (bf16)tile[tx][ty + j * 8];
}

// ---------------- grouped GEMM: C[slot, n] = A[slot, :K] * B_e[n, :K]^T ----------
// FIRST:  A = xb (via slot_tok indirection), B = w1t, Out = Hg (bias+relu+bf16)
// !FIRST: A = Hg (direct slot rows),         B = w2t, Out = Yg (bias, fp32)
template<int KD, int ND, bool FIRST>
__global__ __launch_bounds__(256)
void moe_gemm(const bf16* __restrict__ Adata, const bf16* __restrict__ Bt,
              const float* __restrict__ bias, void* __restrict__ Out,
              const int* __restrict__ slot_tok, const int* __restrict__ offsets,
              const int* __restrict__ tmap_e, const int* __restrict__ tmap_rt,
              const int* __restrict__ ntiles)
{
    const int ty = blockIdx.y;
    if (ty >= *ntiles) return;
    const int e    = tmap_e[ty];
    const int rt   = tmap_rt[ty];
    const int row0 = offsets[e] + rt * 128;
    const int rowEnd = offsets[e + 1];
    const int nb   = blockIdx.x * 128;

    __shared__ __align__(16) bf16 As[128 * 32];
    __shared__ __align__(16) bf16 Bs[128 * 32];

    const int t = threadIdx.x;
    const int w = t >> 6, l = t & 63;
    const int wm = w >> 1, wn = w & 1;

    // staging geometry: 8 chunks of 1KB; wave w stages chunks {2w, 2w+1}
    const int rA0  = (w * 2) * 16 + (l >> 2);
    const int rA1  = (w * 2 + 1) * 16 + (l >> 2);
    const int colb = (l & 3) * 8;

    int srow0 = row0 + rA0; if (srow0 >= NSLOT) srow0 = NSLOT - 1;
    int srow1 = row0 + rA1; if (srow1 >= NSLOT) srow1 = NSLOT - 1;
    const bf16 *aSrc0, *aSrc1;
    if (FIRST) {
        aSrc0 = Adata + (size_t)slot_tok[srow0] * KD + colb;
        aSrc1 = Adata + (size_t)slot_tok[srow1] * KD + colb;
    } else {
        aSrc0 = Adata + (size_t)srow0 * KD + colb;
        aSrc1 = Adata + (size_t)srow1 * KD + colb;
    }
    const bf16* bSrc0 = Bt + ((size_t)e * ND + nb + rA0) * KD + colb;
    const bf16* bSrc1 = Bt + ((size_t)e * ND + nb + rA1) * KD + colb;

    bf16* AsW0 = As + (w * 2) * 512;
    bf16* AsW1 = As + (w * 2 + 1) * 512;
    bf16* BsW0 = Bs + (w * 2) * 512;
    bf16* BsW1 = Bs + (w * 2 + 1) * 512;

    f32x4 acc[4][4] = {};
    const int lr = l & 15;
    const int lk = (l >> 4) * 8;

    for (int k0 = 0; k0 < KD; k0 += 32) {
        gload16(aSrc0 + k0, AsW0);
        gload16(aSrc1 + k0, AsW1);
        gload16(bSrc0 + k0, BsW0);
        gload16(bSrc1 + k0, BsW1);
        __syncthreads();
        bf16x8 aF[4], bF[4];
#pragma unroll
        for (int mi = 0; mi < 4; ++mi)
            aF[mi] = *(const bf16x8*)(As + (wm * 64 + mi * 16 + lr) * 32 + lk);
#pragma unroll
        for (int nj = 0; nj < 4; ++nj)
            bF[nj] = *(const bf16x8*)(Bs + (wn * 64 + nj * 16 + lr) * 32 + lk);
#pragma unroll
        for (int mi = 0; mi < 4; ++mi)
#pragma unroll
            for (int nj = 0; nj < 4; ++nj)
                acc[mi][nj] = __builtin_amdgcn_mfma_f32_16x16x32_bf16(
                    aF[mi], bF[nj], acc[mi][nj], 0, 0, 0);
        __syncthreads();
    }

    const int rowW = row0 + wm * 64;
    const int colW = nb + wn * 64;
#pragma unroll
    for (int mi = 0; mi < 4; ++mi) {
#pragma unroll
        for (int nj = 0; nj < 4; ++nj) {
#pragma unroll
            for (int r = 0; r < 4; ++r) {
                int row = rowW + mi * 16 + (l >> 4) * 4 + r;
                int col = colW + nj * 16 + lr;
                if (row < rowEnd) {
                    float v = acc[mi][nj][r] + bias[e * ND + col];
                    if (FIRST)
                        ((bf16*)Out)[(size_t)row * ND + col] = (bf16)fmaxf(v, 0.f);
                    else
                        ((float*)Out)[(size_t)row * ND + col] = v;
                }
            }
        }
    }
}

// ---------------- combine: out[n] = w0*Y[slot0] + w1*Y[slot1] --------------------
__global__ __launch_bounds__(256)
void combine_kernel(const float* __restrict__ Yg, const int* __restrict__ pos,
                    const float* __restrict__ slot_w, float* __restrict__ out)
{
    int idx = blockIdx.x * 256 + threadIdx.x;  // over NTOK*DDIM/4
    int n = idx >> 7;                           // DDIM/4 = 128
    int d4 = idx & 127;
    int s0 = pos[n * 2 + 0], s1 = pos[n * 2 + 1];
    float w0 = slot_w[s0], w1 = slot_w[s1];
    float4 a = ((const float4*)(Yg + (size_t)s0 * DDIM))[d4];
    float4 b = ((const float4*)(Yg + (size_t)s1 * DDIM))[d4];
    float4 o;
    o.x = w0 * a.x + w1 * b.x;
    o.y = w0 * a.y + w1 * b.y;
    o.z = w0 * a.z + w1 * b.z;
    o.w = w0 * a.w + w1 * b.w;
    ((float4*)out)[idx] = o;
}

extern "C" void kernel_launch(void* const* d_in, const int* in_sizes, int n_in,
                              void* d_out, int out_size, void* d_ws, size_t ws_size,
                              hipStream_t stream)
{
    (void)in_sizes; (void)n_in;
    const float* x  = (const float*)d_in[0];
    const float* Wg = (const float*)d_in[1];
    const float* bg = (const float*)d_in[2];
    const float* W1 = (const float*)d_in[3];
    const float* b1 = (const float*)d_in[4];
    const float* W2 = (const float*)d_in[5];
    const float* b2 = (const float*)d_in[6];
    float* out = (float*)d_out;

    uint8_t* ws = (uint8_t*)d_ws;
    size_t off = 0;
    auto alloc = [&](size_t bytes) -> void* {
        void* p = ws + off;
        off = (off + bytes + 255) & ~(size_t)255;
        return p;
    };
    bf16*  xb      = (bf16*)alloc((size_t)NTOK * DDIM * 2);
    bf16*  w1t     = (bf16*)alloc((size_t)NEXP * FDIM * DDIM * 2);  // [E][FF][D]
    bf16*  w2t     = (bf16*)alloc((size_t)NEXP * DDIM * FDIM * 2);  // [E][D][FF]
    bf16*  Hg      = (bf16*)alloc((size_t)NSLOT * FDIM * 2);
    float* Yg      = (float*)alloc((size_t)NSLOT * DDIM * 4);
    int*   counts  = (int*)alloc(NEXP * 4);
    int*   cursors = (int*)alloc(NEXP * 4);
    int*   offsets = (int*)alloc((NEXP + 1) * 4);
    int*   ntiles  = (int*)alloc(4);
    int*   tmap_e  = (int*)alloc(MAXTILES * 4);
    int*   tmap_rt = (int*)alloc(MAXTILES * 4);
    int*   top_idx = (int*)alloc((size_t)NTOK * 2 * 4);
    float* top_w   = (float*)alloc((size_t)NTOK * 2 * 4);
    int*   pos     = (int*)alloc((size_t)NTOK * 2 * 4);
    int*   slot_tok= (int*)alloc((size_t)NSLOT * 4);
    float* slot_w  = (float*)alloc((size_t)NSLOT * 4);

    if (ws_size < off) {
        // workspace too small: distinguishable failure signature (out = 0)
        hipMemsetAsync(d_out, 0, (size_t)out_size * 4, stream);
        return;
    }

    hipMemsetAsync(counts, 0, NEXP * 4, stream);

    gating_kernel<<<1024, 256, 0, stream>>>(x, Wg, bg, xb, top_idx, top_w, counts);
    scan_kernel<<<1, 64, 0, stream>>>(counts, offsets, tmap_e, tmap_rt, ntiles, cursors);
    scatter_kernel<<<(NTOK + 255) / 256, 256, 0, stream>>>(top_idx, top_w, offsets, cursors,
                                                           slot_tok, slot_w, pos);
    transpose_cvt<<<dim3(FDIM / 32, DDIM / 32, NEXP), 256, 0, stream>>>(W1, w1t, DDIM, FDIM);
    transpose_cvt<<<dim3(DDIM / 32, FDIM / 32, NEXP), 256, 0, stream>>>(W2, w2t, FDIM, DDIM);

    moe_gemm<DDIM, FDIM, true><<<dim3(FDIM / 128, MAXTILES), 256, 0, stream>>>(
        xb, w1t, b1, (void*)Hg, slot_tok, offsets, tmap_e, tmap_rt, ntiles);
    moe_gemm<FDIM, DDIM, false><<<dim3(DDIM / 128, MAXTILES), 256, 0, stream>>>(
        Hg, w2t, b2, (void*)Yg, slot_tok, offsets, tmap_e, tmap_rt, ntiles);

    combine_kernel<<<(NTOK * DDIM / 4) / 256, 256, 0, stream>>>(Yg, pos, slot_w, out);
}

// Round 3
// 209.033 us; speedup vs baseline: 2.1211x; 1.2938x over previous
//
#include <hip/hip_runtime.h>
#include <hip/hip_bf16.h>
#include <cstdint>

// Problem constants (from reference): B=4, T=2048, D=512, FF=2048, E=8, K=2
#define NTOK   8192      // B*T
#define DDIM   512
#define FDIM   2048
#define NEXP   8
#define NSLOT  16384     // 2*NTOK assignments (top-2, always exactly 2 per token)
#define MAXTILES 136     // sum_e ceil(cnt_e/128) <= 16384/128 + 8

typedef __bf16 bf16;
typedef __bf16 bf16x8 __attribute__((ext_vector_type(8)));
typedef float  f32x4  __attribute__((ext_vector_type(4)));

typedef uint32_t __attribute__((address_space(1))) gu32;
typedef uint32_t __attribute__((address_space(3))) lu32;

// async global->LDS, 16B per lane; LDS dest must be wave-uniform base (+lane*16 implicit)
__device__ __forceinline__ void gload16(const void* g, void* l) {
    __builtin_amdgcn_global_load_lds((const gu32*)(uintptr_t)g,
                                     (lu32*)(uintptr_t)l, 16, 0, 0);
}

// ---------------- gating: logits -> softmax -> top2 -> weights; also x->bf16 ----
__global__ __launch_bounds__(256)
void gating_kernel(const float* __restrict__ x, const float* __restrict__ Wg,
                   const float* __restrict__ bg, bf16* __restrict__ xb,
                   int* __restrict__ top_idx, float* __restrict__ top_w,
                   int* __restrict__ counts)
{
    __shared__ int cnt_s[NEXP];
    if (threadIdx.x < NEXP) cnt_s[threadIdx.x] = 0;
    __syncthreads();

    const int w = threadIdx.x >> 6;
    const int l = threadIdx.x & 63;
    const int gw = blockIdx.x * 4 + w;   // 1024 blocks * 4 waves = 4096 waves

    for (int n = gw; n < NTOK; n += 4096) {
        const float4* xp = (const float4*)(x + (size_t)n * DDIM + l * 8);
        float4 x0 = xp[0], x1 = xp[1];
        float xf[8] = {x0.x, x0.y, x0.z, x0.w, x1.x, x1.y, x1.z, x1.w};

        bf16x8 xv;
#pragma unroll
        for (int i = 0; i < 8; ++i) xv[i] = (bf16)xf[i];
        *(bf16x8*)(xb + (size_t)n * DDIM + l * 8) = xv;

        float acc[8] = {0.f,0.f,0.f,0.f,0.f,0.f,0.f,0.f};
#pragma unroll
        for (int i = 0; i < 8; ++i) {
            const float4* wp = (const float4*)(Wg + (size_t)(l * 8 + i) * NEXP);
            float4 wa = wp[0], wb = wp[1];
            acc[0] += xf[i] * wa.x; acc[1] += xf[i] * wa.y;
            acc[2] += xf[i] * wa.z; acc[3] += xf[i] * wa.w;
            acc[4] += xf[i] * wb.x; acc[5] += xf[i] * wb.y;
            acc[6] += xf[i] * wb.z; acc[7] += xf[i] * wb.w;
        }
#pragma unroll
        for (int m = 32; m >= 1; m >>= 1)
#pragma unroll
            for (int e = 0; e < 8; ++e)
                acc[e] += __shfl_xor(acc[e], m);

        if (l == 0) {
            float logit[8];
#pragma unroll
            for (int e = 0; e < 8; ++e) logit[e] = acc[e] + bg[e];
            float mx = logit[0];
#pragma unroll
            for (int e = 1; e < 8; ++e) mx = fmaxf(mx, logit[e]);
            float g[8], s = 0.f;
#pragma unroll
            for (int e = 0; e < 8; ++e) { g[e] = expf(logit[e] - mx); s += g[e]; }
            float inv = 1.f / s;
#pragma unroll
            for (int e = 0; e < 8; ++e) g[e] *= inv;
            // top-2, ties -> lower index first (matches lax.top_k)
            int e0 = 0;
#pragma unroll
            for (int e = 1; e < 8; ++e) if (g[e] > g[e0]) e0 = e;
            int e1 = (e0 == 0) ? 1 : 0;
#pragma unroll
            for (int e = 0; e < 8; ++e) if (e != e0 && e != e1 && g[e] > g[e1]) e1 = e;
            float denom = g[e0] + g[e1] + 0.01f;
            top_idx[n * 2 + 0] = e0;
            top_idx[n * 2 + 1] = e1;
            top_w[n * 2 + 0] = g[e0] / denom;
            top_w[n * 2 + 1] = g[e1] / denom;
            atomicAdd(&cnt_s[e0], 1);
            atomicAdd(&cnt_s[e1], 1);
        }
    }
    __syncthreads();
    if (threadIdx.x < NEXP) atomicAdd(&counts[threadIdx.x], cnt_s[threadIdx.x]);
}

// ---------------- scan: offsets, tile map, zero cursors (single thread, tiny) ----
__global__ void scan_kernel(const int* __restrict__ counts, int* __restrict__ offsets,
                            int* __restrict__ tmap_e, int* __restrict__ tmap_rt,
                            int* __restrict__ ntiles, int* __restrict__ cursors)
{
    if (threadIdx.x == 0) {
        int off = 0;
        for (int e = 0; e < NEXP; ++e) { offsets[e] = off; off += counts[e]; cursors[e] = 0; }
        offsets[NEXP] = off;
        int t = 0;
        for (int e = 0; e < NEXP; ++e) {
            int nt = (counts[e] + 127) >> 7;
            for (int rt = 0; rt < nt; ++rt) { tmap_e[t] = e; tmap_rt[t] = rt; ++t; }
        }
        *ntiles = t;
    }
}

// ---------------- scatter: block-aggregated cursor reservation ------------------
// Slot order within an expert is run-dependent but the final output is
// permutation-invariant (each slot row is a pure function of its token+expert).
__global__ __launch_bounds__(256)
void scatter_kernel(const int* __restrict__ top_idx, const float* __restrict__ top_w,
                    const int* __restrict__ offsets, int* __restrict__ cursors,
                    int* __restrict__ slot_tok, float* __restrict__ slot_w,
                    int* __restrict__ pos)
{
    __shared__ int lcnt[NEXP];
    __shared__ int lbase[NEXP];
    const int t = threadIdx.x;
    if (t < NEXP) lcnt[t] = 0;
    __syncthreads();
    const int n = blockIdx.x * 256 + t;   // NTOK = 32*256 exactly
    const int e0 = top_idx[n * 2 + 0];
    const int e1 = top_idx[n * 2 + 1];
    const int r0 = atomicAdd(&lcnt[e0], 1);
    const int r1 = atomicAdd(&lcnt[e1], 1);
    __syncthreads();
    if (t < NEXP) lbase[t] = atomicAdd(&cursors[t], lcnt[t]);
    __syncthreads();
    const int s0 = offsets[e0] + lbase[e0] + r0;
    const int s1 = offsets[e1] + lbase[e1] + r1;
    slot_tok[s0] = n; slot_w[s0] = top_w[n * 2 + 0]; pos[n * 2 + 0] = s0;
    slot_tok[s1] = n; slot_w[s1] = top_w[n * 2 + 1]; pos[n * 2 + 1] = s1;
}

// ---------------- fp32 [E][R][C] -> bf16 [E][C][R] transpose+convert ------------
// 64x64 tiles; fp32 float4 coalesced loads, bf16x8 (16B) coalesced stores.
__global__ __launch_bounds__(256)
void transpose_cvt(const float* __restrict__ src, bf16* __restrict__ dst, int R, int C)
{
    __shared__ bf16 tile[64][72];   // 72 = 16B-aligned row stride, rotates banks
    const size_t eo = (size_t)blockIdx.z * R * C;
    src += eo; dst += eo;
    const int c0 = blockIdx.x * 64, r0 = blockIdx.y * 64;
    const int tq = (threadIdx.x & 15) * 4;   // col quad within 64
    const int tr = threadIdx.x >> 4;         // 16 rows per pass
#pragma unroll
    for (int j = 0; j < 4; ++j) {
        const int r = tr + j * 16;
        float4 v = *(const float4*)(src + (size_t)(r0 + r) * C + c0 + tq);
        tile[tq + 0][r] = (bf16)v.x;
        tile[tq + 1][r] = (bf16)v.y;
        tile[tq + 2][r] = (bf16)v.z;
        tile[tq + 3][r] = (bf16)v.w;
    }
    __syncthreads();
    const int x8 = (threadIdx.x & 7) * 8;    // 8 bf16 = 16B per store
    const int cr = threadIdx.x >> 3;         // 32 rows per pass
#pragma unroll
    for (int j = 0; j < 2; ++j) {
        const int c = cr + j * 32;
        *(bf16x8*)(dst + (size_t)(c0 + c) * R + r0 + x8) = *(const bf16x8*)&tile[c][x8];
    }
}

// ---------------- grouped GEMM, depth-2 counted-vmcnt pipeline ------------------
// C[slot, n] = A[slot, :K] * B_e[n, :K]^T
// FIRST:  A = xb (via slot_tok indirection), B = w1t, Out = Hg (bias+relu+bf16)
// !FIRST: A = Hg (direct slot rows),         B = w2t, Out = Yg (bias, fp32)
template<int KD, int ND, bool FIRST>
__global__ __launch_bounds__(256)
void moe_gemm(const bf16* __restrict__ Adata, const bf16* __restrict__ Bt,
              const float* __restrict__ bias, void* __restrict__ Out,
              const int* __restrict__ slot_tok, const int* __restrict__ offsets,
              const int* __restrict__ tmap_e, const int* __restrict__ tmap_rt,
              const int* __restrict__ ntiles)
{
    const int ty = blockIdx.y;
    if (ty >= *ntiles) return;
    const int e    = tmap_e[ty];
    const int rt   = tmap_rt[ty];
    const int row0 = offsets[e] + rt * 128;
    const int rowEnd = offsets[e + 1];
    const int nb   = blockIdx.x * 128;

    // double-buffered LDS: [2] x 128x32 bf16 for A and B
    __shared__ __align__(16) bf16 As[2 * 128 * 32];
    __shared__ __align__(16) bf16 Bs[2 * 128 * 32];

    const int t = threadIdx.x;
    const int w = t >> 6, l = t & 63;
    const int wm = w >> 1, wn = w & 1;

    // staging geometry: 8 chunks of 1KB per buffer; wave w stages chunks {2w, 2w+1}
    const int rA0  = (w * 2) * 16 + (l >> 2);
    const int rA1  = (w * 2 + 1) * 16 + (l >> 2);
    const int colb = (l & 3) * 8;

    int srow0 = row0 + rA0; if (srow0 >= NSLOT) srow0 = NSLOT - 1;
    int srow1 = row0 + rA1; if (srow1 >= NSLOT) srow1 = NSLOT - 1;
    const bf16 *aSrc0, *aSrc1;
    if (FIRST) {
        aSrc0 = Adata + (size_t)slot_tok[srow0] * KD + colb;
        aSrc1 = Adata + (size_t)slot_tok[srow1] * KD + colb;
    } else {
        aSrc0 = Adata + (size_t)srow0 * KD + colb;
        aSrc1 = Adata + (size_t)srow1 * KD + colb;
    }
    const bf16* bSrc0 = Bt + ((size_t)e * ND + nb + rA0) * KD + colb;
    const bf16* bSrc1 = Bt + ((size_t)e * ND + nb + rA1) * KD + colb;

    const int offW0 = (w * 2) * 512;
    const int offW1 = (w * 2 + 1) * 512;

    f32x4 acc[4][4] = {};
    const int lr = l & 15;
    const int lk = (l >> 4) * 8;

    constexpr int NT = KD / 32;   // K-tiles (16 or 64) — always >= 2

    // issue tile t's 4 async loads into buffer (t&1)
    auto STAGE = [&](int buf, int k0) {
        bf16* ab = As + buf * 4096;
        bf16* bb = Bs + buf * 4096;
        gload16(aSrc0 + k0, ab + offW0);
        gload16(aSrc1 + k0, ab + offW1);
        gload16(bSrc0 + k0, bb + offW0);
        gload16(bSrc1 + k0, bb + offW1);
    };
    auto COMPUTE = [&](int buf) {
        const bf16* ab = As + buf * 4096;
        const bf16* bb = Bs + buf * 4096;
        bf16x8 aF[4], bF[4];
#pragma unroll
        for (int mi = 0; mi < 4; ++mi)
            aF[mi] = *(const bf16x8*)(ab + (wm * 64 + mi * 16 + lr) * 32 + lk);
#pragma unroll
        for (int nj = 0; nj < 4; ++nj)
            bF[nj] = *(const bf16x8*)(bb + (wn * 64 + nj * 16 + lr) * 32 + lk);
#pragma unroll
        for (int mi = 0; mi < 4; ++mi)
#pragma unroll
            for (int nj = 0; nj < 4; ++nj)
                acc[mi][nj] = __builtin_amdgcn_mfma_f32_16x16x32_bf16(
                    aF[mi], bF[nj], acc[mi][nj], 0, 0, 0);
    };

    // prologue: two tiles in flight
    STAGE(0, 0);
    STAGE(1, 32);
    __builtin_amdgcn_sched_barrier(0);

    for (int t2 = 0; t2 < NT - 1; ++t2) {
        // wait for tile t2's 4 loads (tile t2+1's 4 remain in flight), then sync waves
        asm volatile("s_waitcnt vmcnt(4)" ::: "memory");
        __builtin_amdgcn_s_barrier();
        __builtin_amdgcn_sched_barrier(0);
        COMPUTE(t2 & 1);
        __builtin_amdgcn_s_barrier();            // all waves done reading buf (t2&1)
        __builtin_amdgcn_sched_barrier(0);
        if (t2 + 2 < NT) STAGE(t2 & 1, (t2 + 2) * 32);
        __builtin_amdgcn_sched_barrier(0);
    }
    // last tile: drain everything
    asm volatile("s_waitcnt vmcnt(0)" ::: "memory");
    __builtin_amdgcn_s_barrier();
    __builtin_amdgcn_sched_barrier(0);
    COMPUTE((NT - 1) & 1);

    const int rowW = row0 + wm * 64;
    const int colW = nb + wn * 64;
#pragma unroll
    for (int mi = 0; mi < 4; ++mi) {
#pragma unroll
        for (int nj = 0; nj < 4; ++nj) {
#pragma unroll
            for (int r = 0; r < 4; ++r) {
                int row = rowW + mi * 16 + (l >> 4) * 4 + r;
                int col = colW + nj * 16 + lr;
                if (row < rowEnd) {
                    float v = acc[mi][nj][r] + bias[e * ND + col];
                    if (FIRST)
                        ((bf16*)Out)[(size_t)row * ND + col] = (bf16)fmaxf(v, 0.f);
                    else
                        ((float*)Out)[(size_t)row * ND + col] = v;
                }
            }
        }
    }
}

// ---------------- combine: out[n] = w0*Y[slot0] + w1*Y[slot1] --------------------
__global__ __launch_bounds__(256)
void combine_kernel(const float* __restrict__ Yg, const int* __restrict__ pos,
                    const float* __restrict__ slot_w, float* __restrict__ out)
{
    int idx = blockIdx.x * 256 + threadIdx.x;  // over NTOK*DDIM/4
    int n = idx >> 7;                           // DDIM/4 = 128
    int d4 = idx & 127;
    int s0 = pos[n * 2 + 0], s1 = pos[n * 2 + 1];
    float w0 = slot_w[s0], w1 = slot_w[s1];
    float4 a = ((const float4*)(Yg + (size_t)s0 * DDIM))[d4];
    float4 b = ((const float4*)(Yg + (size_t)s1 * DDIM))[d4];
    float4 o;
    o.x = w0 * a.x + w1 * b.x;
    o.y = w0 * a.y + w1 * b.y;
    o.z = w0 * a.z + w1 * b.z;
    o.w = w0 * a.w + w1 * b.w;
    ((float4*)out)[idx] = o;
}

extern "C" void kernel_launch(void* const* d_in, const int* in_sizes, int n_in,
                              void* d_out, int out_size, void* d_ws, size_t ws_size,
                              hipStream_t stream)
{
    (void)in_sizes; (void)n_in;
    const float* x  = (const float*)d_in[0];
    const float* Wg = (const float*)d_in[1];
    const float* bg = (const float*)d_in[2];
    const float* W1 = (const float*)d_in[3];
    const float* b1 = (const float*)d_in[4];
    const float* W2 = (const float*)d_in[5];
    const float* b2 = (const float*)d_in[6];
    float* out = (float*)d_out;

    uint8_t* ws = (uint8_t*)d_ws;
    size_t off = 0;
    auto alloc = [&](size_t bytes) -> void* {
        void* p = ws + off;
        off = (off + bytes + 255) & ~(size_t)255;
        return p;
    };
    bf16*  xb      = (bf16*)alloc((size_t)NTOK * DDIM * 2);
    bf16*  w1t     = (bf16*)alloc((size_t)NEXP * FDIM * DDIM * 2);  // [E][FF][D]
    bf16*  w2t     = (bf16*)alloc((size_t)NEXP * DDIM * FDIM * 2);  // [E][D][FF]
    bf16*  Hg      = (bf16*)alloc((size_t)NSLOT * FDIM * 2);
    float* Yg      = (float*)alloc((size_t)NSLOT * DDIM * 4);
    int*   counts  = (int*)alloc(NEXP * 4);
    int*   cursors = (int*)alloc(NEXP * 4);
    int*   offsets = (int*)alloc((NEXP + 1) * 4);
    int*   ntiles  = (int*)alloc(4);
    int*   tmap_e  = (int*)alloc(MAXTILES * 4);
    int*   tmap_rt = (int*)alloc(MAXTILES * 4);
    int*   top_idx = (int*)alloc((size_t)NTOK * 2 * 4);
    float* top_w   = (float*)alloc((size_t)NTOK * 2 * 4);
    int*   pos     = (int*)alloc((size_t)NTOK * 2 * 4);
    int*   slot_tok= (int*)alloc((size_t)NSLOT * 4);
    float* slot_w  = (float*)alloc((size_t)NSLOT * 4);

    if (ws_size < off) {
        // workspace too small: distinguishable failure signature (out = 0)
        hipMemsetAsync(d_out, 0, (size_t)out_size * 4, stream);
        return;
    }

    hipMemsetAsync(counts, 0, NEXP * 4, stream);

    gating_kernel<<<1024, 256, 0, stream>>>(x, Wg, bg, xb, top_idx, top_w, counts);
    scan_kernel<<<1, 64, 0, stream>>>(counts, offsets, tmap_e, tmap_rt, ntiles, cursors);
    scatter_kernel<<<NTOK / 256, 256, 0, stream>>>(top_idx, top_w, offsets, cursors,
                                                   slot_tok, slot_w, pos);
    transpose_cvt<<<dim3(FDIM / 64, DDIM / 64, NEXP), 256, 0, stream>>>(W1, w1t, DDIM, FDIM);
    transpose_cvt<<<dim3(DDIM / 64, FDIM / 64, NEXP), 256, 0, stream>>>(W2, w2t, FDIM, DDIM);

    moe_gemm<DDIM, FDIM, true><<<dim3(FDIM / 128, MAXTILES), 256, 0, stream>>>(
        xb, w1t, b1, (void*)Hg, slot_tok, offsets, tmap_e, tmap_rt, ntiles);
    moe_gemm<FDIM, DDIM, false><<<dim3(DDIM / 128, MAXTILES), 256, 0, stream>>>(
        Hg, w2t, b2, (void*)Yg, slot_tok, offsets, tmap_e, tmap_rt, ntiles);

    combine_kernel<<<(NTOK * DDIM / 4) / 256, 256, 0, stream>>>(Yg, pos, slot_w, out);
}

// Round 4
// 205.596 us; speedup vs baseline: 2.1566x; 1.0167x over previous
//
#include <hip/hip_runtime.h>
#include <hip/hip_bf16.h>
#include <cstdint>

// Problem constants (from reference): B=4, T=2048, D=512, FF=2048, E=8, K=2
#define NTOK   8192      // B*T
#define DDIM   512
#define FDIM   2048
#define NEXP   8
#define NSLOT  16384     // 2*NTOK assignments (top-2, always exactly 2 per token)
#define MAXTILES 136     // sum_e ceil(cnt_e/128) <= 16384/128 + 8

typedef __bf16 bf16;
typedef __bf16 bf16x8 __attribute__((ext_vector_type(8)));
typedef float  f32x4  __attribute__((ext_vector_type(4)));

typedef uint32_t __attribute__((address_space(1))) gu32;
typedef uint32_t __attribute__((address_space(3))) lu32;

// async global->LDS, 16B per lane; LDS dest must be wave-uniform base (+lane*16 implicit)
__device__ __forceinline__ void gload16(const void* g, void* l) {
    __builtin_amdgcn_global_load_lds((const gu32*)(uintptr_t)g,
                                     (lu32*)(uintptr_t)l, 16, 0, 0);
}

// ---------------- gating: logits -> softmax -> top2 -> weights; also x->bf16 ----
__global__ __launch_bounds__(256)
void gating_kernel(const float* __restrict__ x, const float* __restrict__ Wg,
                   const float* __restrict__ bg, bf16* __restrict__ xb,
                   int* __restrict__ top_idx, float* __restrict__ top_w,
                   int* __restrict__ counts)
{
    __shared__ int cnt_s[NEXP];
    if (threadIdx.x < NEXP) cnt_s[threadIdx.x] = 0;
    __syncthreads();

    const int w = threadIdx.x >> 6;
    const int l = threadIdx.x & 63;
    const int gw = blockIdx.x * 4 + w;   // 1024 blocks * 4 waves = 4096 waves

    for (int n = gw; n < NTOK; n += 4096) {
        const float4* xp = (const float4*)(x + (size_t)n * DDIM + l * 8);
        float4 x0 = xp[0], x1 = xp[1];
        float xf[8] = {x0.x, x0.y, x0.z, x0.w, x1.x, x1.y, x1.z, x1.w};

        bf16x8 xv;
#pragma unroll
        for (int i = 0; i < 8; ++i) xv[i] = (bf16)xf[i];
        *(bf16x8*)(xb + (size_t)n * DDIM + l * 8) = xv;

        float acc[8] = {0.f,0.f,0.f,0.f,0.f,0.f,0.f,0.f};
#pragma unroll
        for (int i = 0; i < 8; ++i) {
            const float4* wp = (const float4*)(Wg + (size_t)(l * 8 + i) * NEXP);
            float4 wa = wp[0], wb = wp[1];
            acc[0] += xf[i] * wa.x; acc[1] += xf[i] * wa.y;
            acc[2] += xf[i] * wa.z; acc[3] += xf[i] * wa.w;
            acc[4] += xf[i] * wb.x; acc[5] += xf[i] * wb.y;
            acc[6] += xf[i] * wb.z; acc[7] += xf[i] * wb.w;
        }
#pragma unroll
        for (int m = 32; m >= 1; m >>= 1)
#pragma unroll
            for (int e = 0; e < 8; ++e)
                acc[e] += __shfl_xor(acc[e], m);

        if (l == 0) {
            float logit[8];
#pragma unroll
            for (int e = 0; e < 8; ++e) logit[e] = acc[e] + bg[e];
            float mx = logit[0];
#pragma unroll
            for (int e = 1; e < 8; ++e) mx = fmaxf(mx, logit[e]);
            float g[8], s = 0.f;
#pragma unroll
            for (int e = 0; e < 8; ++e) { g[e] = expf(logit[e] - mx); s += g[e]; }
            float inv = 1.f / s;
#pragma unroll
            for (int e = 0; e < 8; ++e) g[e] *= inv;
            // top-2, ties -> lower index first (matches lax.top_k)
            int e0 = 0;
#pragma unroll
            for (int e = 1; e < 8; ++e) if (g[e] > g[e0]) e0 = e;
            int e1 = (e0 == 0) ? 1 : 0;
#pragma unroll
            for (int e = 0; e < 8; ++e) if (e != e0 && e != e1 && g[e] > g[e1]) e1 = e;
            float denom = g[e0] + g[e1] + 0.01f;
            top_idx[n * 2 + 0] = e0;
            top_idx[n * 2 + 1] = e1;
            top_w[n * 2 + 0] = g[e0] / denom;
            top_w[n * 2 + 1] = g[e1] / denom;
            atomicAdd(&cnt_s[e0], 1);
            atomicAdd(&cnt_s[e1], 1);
        }
    }
    __syncthreads();
    if (threadIdx.x < NEXP) atomicAdd(&counts[threadIdx.x], cnt_s[threadIdx.x]);
}

// ---------------- scan: offsets, tile map, zero cursors (single thread, tiny) ----
__global__ void scan_kernel(const int* __restrict__ counts, int* __restrict__ offsets,
                            int* __restrict__ tmap_e, int* __restrict__ tmap_rt,
                            int* __restrict__ ntiles, int* __restrict__ cursors)
{
    if (threadIdx.x == 0) {
        int off = 0;
        for (int e = 0; e < NEXP; ++e) { offsets[e] = off; off += counts[e]; cursors[e] = 0; }
        offsets[NEXP] = off;
        int t = 0;
        for (int e = 0; e < NEXP; ++e) {
            int nt = (counts[e] + 127) >> 7;
            for (int rt = 0; rt < nt; ++rt) { tmap_e[t] = e; tmap_rt[t] = rt; ++t; }
        }
        *ntiles = t;
    }
}

// ---------------- scatter: block-aggregated cursor reservation ------------------
__global__ __launch_bounds__(256)
void scatter_kernel(const int* __restrict__ top_idx, const float* __restrict__ top_w,
                    const int* __restrict__ offsets, int* __restrict__ cursors,
                    int* __restrict__ slot_tok, float* __restrict__ slot_w,
                    int* __restrict__ pos)
{
    __shared__ int lcnt[NEXP];
    __shared__ int lbase[NEXP];
    const int t = threadIdx.x;
    if (t < NEXP) lcnt[t] = 0;
    __syncthreads();
    const int n = blockIdx.x * 256 + t;   // NTOK = 32*256 exactly
    const int e0 = top_idx[n * 2 + 0];
    const int e1 = top_idx[n * 2 + 1];
    const int r0 = atomicAdd(&lcnt[e0], 1);
    const int r1 = atomicAdd(&lcnt[e1], 1);
    __syncthreads();
    if (t < NEXP) lbase[t] = atomicAdd(&cursors[t], lcnt[t]);
    __syncthreads();
    const int s0 = offsets[e0] + lbase[e0] + r0;
    const int s1 = offsets[e1] + lbase[e1] + r1;
    slot_tok[s0] = n; slot_w[s0] = top_w[n * 2 + 0]; pos[n * 2 + 0] = s0;
    slot_tok[s1] = n; slot_w[s1] = top_w[n * 2 + 1]; pos[n * 2 + 1] = s1;
}

// ---------------- fp32 [E][R][C] -> bf16 [E][C][R] transpose+convert ------------
__global__ __launch_bounds__(256)
void transpose_cvt(const float* __restrict__ src, bf16* __restrict__ dst, int R, int C)
{
    __shared__ bf16 tile[64][72];   // 72 = 16B-aligned row stride, rotates banks
    const size_t eo = (size_t)blockIdx.z * R * C;
    src += eo; dst += eo;
    const int c0 = blockIdx.x * 64, r0 = blockIdx.y * 64;
    const int tq = (threadIdx.x & 15) * 4;   // col quad within 64
    const int tr = threadIdx.x >> 4;         // 16 rows per pass
#pragma unroll
    for (int j = 0; j < 4; ++j) {
        const int r = tr + j * 16;
        float4 v = *(const float4*)(src + (size_t)(r0 + r) * C + c0 + tq);
        tile[tq + 0][r] = (bf16)v.x;
        tile[tq + 1][r] = (bf16)v.y;
        tile[tq + 2][r] = (bf16)v.z;
        tile[tq + 3][r] = (bf16)v.w;
    }
    __syncthreads();
    const int x8 = (threadIdx.x & 7) * 8;    // 8 bf16 = 16B per store
    const int cr = threadIdx.x >> 3;         // 32 rows per pass
#pragma unroll
    for (int j = 0; j < 2; ++j) {
        const int c = cr + j * 32;
        *(bf16x8*)(dst + (size_t)(c0 + c) * R + r0 + x8) = *(const bf16x8*)&tile[c][x8];
    }
}

// ---------------- grouped GEMM, 8-wave, depth-4 counted-vmcnt pipeline ----------
// C[slot, n] = A[slot, :K] * B_e[n, :K]^T
// FIRST:  A = xb (via slot_tok indirection), B = w1t, Out = Hg (bias+relu+bf16)
// !FIRST: A = Hg (direct slot rows),         B = w2t, Out = Yg (bias, fp32)
// 512 threads = 8 waves (wave grid 4x2, each wave 32x64 output).
// LDS: 4 tile-buffers x (8KB A + 8KB B) = 64KB -> 2 blocks/CU = 16 waves/CU.
// Steady-state wait: vmcnt(6) -> a tile's 2 loads issued 3 iterations before use.
template<int KD, int ND, bool FIRST>
__global__ __launch_bounds__(512)
void moe_gemm(const bf16* __restrict__ Adata, const bf16* __restrict__ Bt,
              const float* __restrict__ bias, void* __restrict__ Out,
              const int* __restrict__ slot_tok, const int* __restrict__ offsets,
              const int* __restrict__ tmap_e, const int* __restrict__ tmap_rt,
              const int* __restrict__ ntiles)
{
    const int ty = blockIdx.y;
    if (ty >= *ntiles) return;
    const int e    = tmap_e[ty];
    const int rt   = tmap_rt[ty];
    const int row0 = offsets[e] + rt * 128;
    const int rowEnd = offsets[e + 1];
    const int nb   = blockIdx.x * 128;

    // quad-buffered LDS: [4] x 128x32 bf16 for A and B
    __shared__ __align__(16) bf16 As[4 * 128 * 32];
    __shared__ __align__(16) bf16 Bs[4 * 128 * 32];

    const int t = threadIdx.x;
    const int w = t >> 6, l = t & 63;      // 8 waves
    const int wm = w >> 1, wn = w & 1;     // 4x2 wave grid

    // staging: wave w stages rows w*16 .. w*16+15 of A-tile and B-tile (1KB each)
    const int rA   = w * 16 + (l >> 2);
    const int colb = (l & 3) * 8;

    int srow = row0 + rA; if (srow >= NSLOT) srow = NSLOT - 1;
    const bf16* aSrc;
    if (FIRST) aSrc = Adata + (size_t)slot_tok[srow] * KD + colb;
    else       aSrc = Adata + (size_t)srow * KD + colb;
    const bf16* bSrc = Bt + ((size_t)e * ND + nb + rA) * KD + colb;

    const int offW = w * 512;   // elem offset of this wave's 1KB chunk

    f32x4 acc[2][4] = {};
    const int lr = l & 15;
    const int lk = (l >> 4) * 8;

    constexpr int NT = KD / 32;   // K-tiles: 16 (GEMM1) or 64 (GEMM2), >= 8

    auto STAGE = [&](int buf, int k0) {
        gload16(aSrc + k0, As + buf * 4096 + offW);
        gload16(bSrc + k0, Bs + buf * 4096 + offW);
    };
    auto COMPUTE = [&](int buf) {
        const bf16* ab = As + buf * 4096;
        const bf16* bb = Bs + buf * 4096;
        bf16x8 aF[2], bF[4];
#pragma unroll
        for (int mi = 0; mi < 2; ++mi)
            aF[mi] = *(const bf16x8*)(ab + (wm * 32 + mi * 16 + lr) * 32 + lk);
#pragma unroll
        for (int nj = 0; nj < 4; ++nj)
            bF[nj] = *(const bf16x8*)(bb + (wn * 64 + nj * 16 + lr) * 32 + lk);
#pragma unroll
        for (int mi = 0; mi < 2; ++mi)
#pragma unroll
            for (int nj = 0; nj < 4; ++nj)
                acc[mi][nj] = __builtin_amdgcn_mfma_f32_16x16x32_bf16(
                    aF[mi], bF[nj], acc[mi][nj], 0, 0, 0);
    };

    // prologue: 4 tiles in flight (8 loads/wave)
    STAGE(0, 0);
    STAGE(1, 32);
    STAGE(2, 64);
    STAGE(3, 96);
    __builtin_amdgcn_sched_barrier(0);

    for (int t2 = 0; t2 < NT - 4; ++t2) {
        // wait for tile t2's 2 loads (3 younger tiles' 6 loads stay in flight)
        asm volatile("s_waitcnt vmcnt(6)" ::: "memory");
        __builtin_amdgcn_sched_barrier(0);
        __builtin_amdgcn_s_barrier();
        __builtin_amdgcn_sched_barrier(0);
        COMPUTE(t2 & 3);
        __builtin_amdgcn_s_barrier();            // all waves done reading buf (t2&3)
        __builtin_amdgcn_sched_barrier(0);
        STAGE(t2 & 3, (t2 + 4) * 32);
        __builtin_amdgcn_sched_barrier(0);
    }
    // tail: drain 4 remaining tiles, vmcnt 6 -> 4 -> 2 -> 0
    asm volatile("s_waitcnt vmcnt(6)" ::: "memory");
    __builtin_amdgcn_sched_barrier(0);
    __builtin_amdgcn_s_barrier();
    __builtin_amdgcn_sched_barrier(0);
    COMPUTE((NT - 4) & 3);
    asm volatile("s_waitcnt vmcnt(4)" ::: "memory");
    __builtin_amdgcn_sched_barrier(0);
    __builtin_amdgcn_s_barrier();
    __builtin_amdgcn_sched_barrier(0);
    COMPUTE((NT - 3) & 3);
    asm volatile("s_waitcnt vmcnt(2)" ::: "memory");
    __builtin_amdgcn_sched_barrier(0);
    __builtin_amdgcn_s_barrier();
    __builtin_amdgcn_sched_barrier(0);
    COMPUTE((NT - 2) & 3);
    asm volatile("s_waitcnt vmcnt(0)" ::: "memory");
    __builtin_amdgcn_sched_barrier(0);
    __builtin_amdgcn_s_barrier();
    __builtin_amdgcn_sched_barrier(0);
    COMPUTE((NT - 1) & 3);

    const int rowW = row0 + wm * 32;
    const int colW = nb + wn * 64;
#pragma unroll
    for (int mi = 0; mi < 2; ++mi) {
#pragma unroll
        for (int nj = 0; nj < 4; ++nj) {
#pragma unroll
            for (int r = 0; r < 4; ++r) {
                int row = rowW + mi * 16 + (l >> 4) * 4 + r;
                int col = colW + nj * 16 + lr;
                if (row < rowEnd) {
                    float v = acc[mi][nj][r] + bias[e * ND + col];
                    if (FIRST)
                        ((bf16*)Out)[(size_t)row * ND + col] = (bf16)fmaxf(v, 0.f);
                    else
                        ((float*)Out)[(size_t)row * ND + col] = v;
                }
            }
        }
    }
}

// ---------------- combine: out[n] = w0*Y[slot0] + w1*Y[slot1] --------------------
__global__ __launch_bounds__(256)
void combine_kernel(const float* __restrict__ Yg, const int* __restrict__ pos,
                    const float* __restrict__ slot_w, float* __restrict__ out)
{
    int idx = blockIdx.x * 256 + threadIdx.x;  // over NTOK*DDIM/4
    int n = idx >> 7;                           // DDIM/4 = 128
    int d4 = idx & 127;
    int s0 = pos[n * 2 + 0], s1 = pos[n * 2 + 1];
    float w0 = slot_w[s0], w1 = slot_w[s1];
    float4 a = ((const float4*)(Yg + (size_t)s0 * DDIM))[d4];
    float4 b = ((const float4*)(Yg + (size_t)s1 * DDIM))[d4];
    float4 o;
    o.x = w0 * a.x + w1 * b.x;
    o.y = w0 * a.y + w1 * b.y;
    o.z = w0 * a.z + w1 * b.z;
    o.w = w0 * a.w + w1 * b.w;
    ((float4*)out)[idx] = o;
}

extern "C" void kernel_launch(void* const* d_in, const int* in_sizes, int n_in,
                              void* d_out, int out_size, void* d_ws, size_t ws_size,
                              hipStream_t stream)
{
    (void)in_sizes; (void)n_in;
    const float* x  = (const float*)d_in[0];
    const float* Wg = (const float*)d_in[1];
    const float* bg = (const float*)d_in[2];
    const float* W1 = (const float*)d_in[3];
    const float* b1 = (const float*)d_in[4];
    const float* W2 = (const float*)d_in[5];
    const float* b2 = (const float*)d_in[6];
    float* out = (float*)d_out;

    uint8_t* ws = (uint8_t*)d_ws;
    size_t off = 0;
    auto alloc = [&](size_t bytes) -> void* {
        void* p = ws + off;
        off = (off + bytes + 255) & ~(size_t)255;
        return p;
    };
    bf16*  xb      = (bf16*)alloc((size_t)NTOK * DDIM * 2);
    bf16*  w1t     = (bf16*)alloc((size_t)NEXP * FDIM * DDIM * 2);  // [E][FF][D]
    bf16*  w2t     = (bf16*)alloc((size_t)NEXP * DDIM * FDIM * 2);  // [E][D][FF]
    bf16*  Hg      = (bf16*)alloc((size_t)NSLOT * FDIM * 2);
    float* Yg      = (float*)alloc((size_t)NSLOT * DDIM * 4);
    int*   counts  = (int*)alloc(NEXP * 4);
    int*   cursors = (int*)alloc(NEXP * 4);
    int*   offsets = (int*)alloc((NEXP + 1) * 4);
    int*   ntiles  = (int*)alloc(4);
    int*   tmap_e  = (int*)alloc(MAXTILES * 4);
    int*   tmap_rt = (int*)alloc(MAXTILES * 4);
    int*   top_idx = (int*)alloc((size_t)NTOK * 2 * 4);
    float* top_w   = (float*)alloc((size_t)NTOK * 2 * 4);
    int*   pos     = (int*)alloc((size_t)NTOK * 2 * 4);
    int*   slot_tok= (int*)alloc((size_t)NSLOT * 4);
    float* slot_w  = (float*)alloc((size_t)NSLOT * 4);

    if (ws_size < off) {
        // workspace too small: distinguishable failure signature (out = 0)
        hipMemsetAsync(d_out, 0, (size_t)out_size * 4, stream);
        return;
    }

    hipMemsetAsync(counts, 0, NEXP * 4, stream);

    gating_kernel<<<1024, 256, 0, stream>>>(x, Wg, bg, xb, top_idx, top_w, counts);
    scan_kernel<<<1, 64, 0, stream>>>(counts, offsets, tmap_e, tmap_rt, ntiles, cursors);
    scatter_kernel<<<NTOK / 256, 256, 0, stream>>>(top_idx, top_w, offsets, cursors,
                                                   slot_tok, slot_w, pos);
    transpose_cvt<<<dim3(FDIM / 64, DDIM / 64, NEXP), 256, 0, stream>>>(W1, w1t, DDIM, FDIM);
    transpose_cvt<<<dim3(DDIM / 64, FDIM / 64, NEXP), 256, 0, stream>>>(W2, w2t, FDIM, DDIM);

    moe_gemm<DDIM, FDIM, true><<<dim3(FDIM / 128, MAXTILES), 512, 0, stream>>>(
        xb, w1t, b1, (void*)Hg, slot_tok, offsets, tmap_e, tmap_rt, ntiles);
    moe_gemm<FDIM, DDIM, false><<<dim3(DDIM / 128, MAXTILES), 512, 0, stream>>>(
        Hg, w2t, b2, (void*)Yg, slot_tok, offsets, tmap_e, tmap_rt, ntiles);

    combine_kernel<<<(NTOK * DDIM / 4) / 256, 256, 0, stream>>>(Yg, pos, slot_w, out);
}

// Round 5
// 184.466 us; speedup vs baseline: 2.4036x; 1.1145x over previous
//
#include <hip/hip_runtime.h>
#include <hip/hip_bf16.h>
#include <cstdint>

// Problem constants (from reference): B=4, T=2048, D=512, FF=2048, E=8, K=2
#define NTOK   8192      // B*T
#define DDIM   512
#define FDIM   2048
#define NEXP   8
#define NSLOT  16384     // 2*NTOK assignments (top-2, always exactly 2 per token)
#define MAXTILES 136     // sum_e ceil(cnt_e/128) <= 16384/128 + 8

typedef __bf16 bf16;
typedef __bf16 bf16x8 __attribute__((ext_vector_type(8)));
typedef float  f32x4  __attribute__((ext_vector_type(4)));

typedef uint32_t __attribute__((address_space(1))) gu32;
typedef uint32_t __attribute__((address_space(3))) lu32;

// async global->LDS, 16B per lane; LDS dest must be wave-uniform base (+lane*16 implicit)
__device__ __forceinline__ void gload16(const void* g, void* l) {
    __builtin_amdgcn_global_load_lds((const gu32*)(uintptr_t)g,
                                     (lu32*)(uintptr_t)l, 16, 0, 0);
}

// ---------------- gating: logits -> softmax -> top2 -> weights; also x->bf16 ----
__global__ __launch_bounds__(256)
void gating_kernel(const float* __restrict__ x, const float* __restrict__ Wg,
                   const float* __restrict__ bg, bf16* __restrict__ xb,
                   int* __restrict__ top_idx, float* __restrict__ top_w,
                   int* __restrict__ counts)
{
    __shared__ int cnt_s[NEXP];
    if (threadIdx.x < NEXP) cnt_s[threadIdx.x] = 0;
    __syncthreads();

    const int w = threadIdx.x >> 6;
    const int l = threadIdx.x & 63;
    const int gw = blockIdx.x * 4 + w;   // 1024 blocks * 4 waves = 4096 waves

    for (int n = gw; n < NTOK; n += 4096) {
        const float4* xp = (const float4*)(x + (size_t)n * DDIM + l * 8);
        float4 x0 = xp[0], x1 = xp[1];
        float xf[8] = {x0.x, x0.y, x0.z, x0.w, x1.x, x1.y, x1.z, x1.w};

        bf16x8 xv;
#pragma unroll
        for (int i = 0; i < 8; ++i) xv[i] = (bf16)xf[i];
        *(bf16x8*)(xb + (size_t)n * DDIM + l * 8) = xv;

        float acc[8] = {0.f,0.f,0.f,0.f,0.f,0.f,0.f,0.f};
#pragma unroll
        for (int i = 0; i < 8; ++i) {
            const float4* wp = (const float4*)(Wg + (size_t)(l * 8 + i) * NEXP);
            float4 wa = wp[0], wb = wp[1];
            acc[0] += xf[i] * wa.x; acc[1] += xf[i] * wa.y;
            acc[2] += xf[i] * wa.z; acc[3] += xf[i] * wa.w;
            acc[4] += xf[i] * wb.x; acc[5] += xf[i] * wb.y;
            acc[6] += xf[i] * wb.z; acc[7] += xf[i] * wb.w;
        }
#pragma unroll
        for (int m = 32; m >= 1; m >>= 1)
#pragma unroll
            for (int e = 0; e < 8; ++e)
                acc[e] += __shfl_xor(acc[e], m);

        if (l == 0) {
            float logit[8];
#pragma unroll
            for (int e = 0; e < 8; ++e) logit[e] = acc[e] + bg[e];
            float mx = logit[0];
#pragma unroll
            for (int e = 1; e < 8; ++e) mx = fmaxf(mx, logit[e]);
            float g[8], s = 0.f;
#pragma unroll
            for (int e = 0; e < 8; ++e) { g[e] = expf(logit[e] - mx); s += g[e]; }
            float inv = 1.f / s;
#pragma unroll
            for (int e = 0; e < 8; ++e) g[e] *= inv;
            // top-2, ties -> lower index first (matches lax.top_k)
            int e0 = 0;
#pragma unroll
            for (int e = 1; e < 8; ++e) if (g[e] > g[e0]) e0 = e;
            int e1 = (e0 == 0) ? 1 : 0;
#pragma unroll
            for (int e = 0; e < 8; ++e) if (e != e0 && e != e1 && g[e] > g[e1]) e1 = e;
            float denom = g[e0] + g[e1] + 0.01f;
            top_idx[n * 2 + 0] = e0;
            top_idx[n * 2 + 1] = e1;
            top_w[n * 2 + 0] = g[e0] / denom;
            top_w[n * 2 + 1] = g[e1] / denom;
            atomicAdd(&cnt_s[e0], 1);
            atomicAdd(&cnt_s[e1], 1);
        }
    }
    __syncthreads();
    if (threadIdx.x < NEXP) atomicAdd(&counts[threadIdx.x], cnt_s[threadIdx.x]);
}

// ---------------- scan: offsets, tile map, zero cursors (single thread, tiny) ----
__global__ void scan_kernel(const int* __restrict__ counts, int* __restrict__ offsets,
                            int* __restrict__ tmap_e, int* __restrict__ tmap_rt,
                            int* __restrict__ ntiles, int* __restrict__ cursors)
{
    if (threadIdx.x == 0) {
        int off = 0;
        for (int e = 0; e < NEXP; ++e) { offsets[e] = off; off += counts[e]; cursors[e] = 0; }
        offsets[NEXP] = off;
        int t = 0;
        for (int e = 0; e < NEXP; ++e) {
            int nt = (counts[e] + 127) >> 7;
            for (int rt = 0; rt < nt; ++rt) { tmap_e[t] = e; tmap_rt[t] = rt; ++t; }
        }
        *ntiles = t;
    }
}

// ---------------- scatter: block-aggregated cursor reservation ------------------
__global__ __launch_bounds__(256)
void scatter_kernel(const int* __restrict__ top_idx, const float* __restrict__ top_w,
                    const int* __restrict__ offsets, int* __restrict__ cursors,
                    int* __restrict__ slot_tok, float* __restrict__ slot_w,
                    int* __restrict__ pos)
{
    __shared__ int lcnt[NEXP];
    __shared__ int lbase[NEXP];
    const int t = threadIdx.x;
    if (t < NEXP) lcnt[t] = 0;
    __syncthreads();
    const int n = blockIdx.x * 256 + t;   // NTOK = 32*256 exactly
    const int e0 = top_idx[n * 2 + 0];
    const int e1 = top_idx[n * 2 + 1];
    const int r0 = atomicAdd(&lcnt[e0], 1);
    const int r1 = atomicAdd(&lcnt[e1], 1);
    __syncthreads();
    if (t < NEXP) lbase[t] = atomicAdd(&cursors[t], lcnt[t]);
    __syncthreads();
    const int s0 = offsets[e0] + lbase[e0] + r0;
    const int s1 = offsets[e1] + lbase[e1] + r1;
    slot_tok[s0] = n; slot_w[s0] = top_w[n * 2 + 0]; pos[n * 2 + 0] = s0;
    slot_tok[s1] = n; slot_w[s1] = top_w[n * 2 + 1]; pos[n * 2 + 1] = s1;
}

// ---------------- fp32 [E][R][C] -> bf16 [E][C][R] transpose+convert ------------
__global__ __launch_bounds__(256)
void transpose_cvt(const float* __restrict__ src, bf16* __restrict__ dst, int R, int C)
{
    __shared__ bf16 tile[64][72];   // 72 = 16B-aligned row stride, rotates banks
    const size_t eo = (size_t)blockIdx.z * R * C;
    src += eo; dst += eo;
    const int c0 = blockIdx.x * 64, r0 = blockIdx.y * 64;
    const int tq = (threadIdx.x & 15) * 4;   // col quad within 64
    const int tr = threadIdx.x >> 4;         // 16 rows per pass
#pragma unroll
    for (int j = 0; j < 4; ++j) {
        const int r = tr + j * 16;
        float4 v = *(const float4*)(src + (size_t)(r0 + r) * C + c0 + tq);
        tile[tq + 0][r] = (bf16)v.x;
        tile[tq + 1][r] = (bf16)v.y;
        tile[tq + 2][r] = (bf16)v.z;
        tile[tq + 3][r] = (bf16)v.w;
    }
    __syncthreads();
    const int x8 = (threadIdx.x & 7) * 8;    // 8 bf16 = 16B per store
    const int cr = threadIdx.x >> 3;         // 32 rows per pass
#pragma unroll
    for (int j = 0; j < 2; ++j) {
        const int c = cr + j * 32;
        *(bf16x8*)(dst + (size_t)(c0 + c) * R + r0 + x8) = *(const bf16x8*)&tile[c][x8];
    }
}

// ---------------- grouped GEMM, 8-wave, depth-3 counted-vmcnt + XCD swizzle ------
// C[slot, n] = A[slot, :K] * B_e[n, :K]^T
// FIRST:  A = xb (via slot_tok indirection), B = w1t, Out = Hg (bias+relu+bf16)
// !FIRST: A = Hg (direct slot rows),         B = w2t, Out = Yg (bias, fp32)
// 512 threads = 8 waves (wave grid 4x2, each wave 32x64 output).
// LDS: 3 tile-buffers x (8KB A + 8KB B) = 48KB -> 3 blocks/CU = 24 waves/CU.
// XCD swizzle: each XCD gets a contiguous x-fastest work chunk so the N-tiles
// sharing an A row-panel hit the same per-XCD L2 (FETCH ideal: A once per XCD).
template<int KD, int ND, bool FIRST>
__global__ __launch_bounds__(512)
void moe_gemm(const bf16* __restrict__ Adata, const bf16* __restrict__ Bt,
              const float* __restrict__ bias, void* __restrict__ Out,
              const int* __restrict__ slot_tok, const int* __restrict__ offsets,
              const int* __restrict__ tmap_e, const int* __restrict__ tmap_rt,
              const int* __restrict__ ntiles)
{
    constexpr int NX  = ND / 128;          // N-tiles: 16 (GEMM1) or 4 (GEMM2)
    constexpr int NWG = NX * MAXTILES;     // 2176 / 544 — both % 8 == 0
    constexpr int Q   = NWG / 8;

    const int orig = blockIdx.y * NX + blockIdx.x;       // HW dispatch order
    const int work = (orig & 7) * Q + (orig >> 3);       // bijective XCD chunking
    const int wy   = work / NX;                          // row-tile
    const int wx   = work - wy * NX;                     // N-tile
    if (wy >= *ntiles) return;

    const int e    = tmap_e[wy];
    const int rt   = tmap_rt[wy];
    const int row0 = offsets[e] + rt * 128;
    const int rowEnd = offsets[e + 1];
    const int nb   = wx * 128;

    // triple-buffered LDS: [3] x 128x32 bf16 for A and B
    __shared__ __align__(16) bf16 As[3 * 128 * 32];
    __shared__ __align__(16) bf16 Bs[3 * 128 * 32];

    const int t = threadIdx.x;
    const int w = t >> 6, l = t & 63;      // 8 waves
    const int wm = w >> 1, wn = w & 1;     // 4x2 wave grid

    // staging: wave w stages rows w*16 .. w*16+15 of A-tile and B-tile (1KB each)
    const int rA   = w * 16 + (l >> 2);
    const int colb = (l & 3) * 8;

    int srow = row0 + rA; if (srow >= NSLOT) srow = NSLOT - 1;
    const bf16* aSrc;
    if (FIRST) aSrc = Adata + (size_t)slot_tok[srow] * KD + colb;
    else       aSrc = Adata + (size_t)srow * KD + colb;
    const bf16* bSrc = Bt + ((size_t)e * ND + nb + rA) * KD + colb;

    const int offW = w * 512;   // elem offset of this wave's 1KB chunk

    f32x4 acc[2][4] = {};
    const int lr = l & 15;
    const int lk = (l >> 4) * 8;

    constexpr int NT = KD / 32;   // K-tiles: 16 (GEMM1) or 64 (GEMM2)

    auto STAGE = [&](int buf, int k0) {
        gload16(aSrc + k0, As + buf * 4096 + offW);
        gload16(bSrc + k0, Bs + buf * 4096 + offW);
    };
    auto COMPUTE = [&](int buf) {
        const bf16* ab = As + buf * 4096;
        const bf16* bb = Bs + buf * 4096;
        bf16x8 aF[2], bF[4];
#pragma unroll
        for (int mi = 0; mi < 2; ++mi)
            aF[mi] = *(const bf16x8*)(ab + (wm * 32 + mi * 16 + lr) * 32 + lk);
#pragma unroll
        for (int nj = 0; nj < 4; ++nj)
            bF[nj] = *(const bf16x8*)(bb + (wn * 64 + nj * 16 + lr) * 32 + lk);
#pragma unroll
        for (int mi = 0; mi < 2; ++mi)
#pragma unroll
            for (int nj = 0; nj < 4; ++nj)
                acc[mi][nj] = __builtin_amdgcn_mfma_f32_16x16x32_bf16(
                    aF[mi], bF[nj], acc[mi][nj], 0, 0, 0);
    };

    // prologue: 3 tiles in flight (6 loads/wave)
    STAGE(0, 0);
    STAGE(1, 32);
    STAGE(2, 64);
    __builtin_amdgcn_sched_barrier(0);

    int buf = 0;
    for (int t2 = 0; t2 < NT - 3; ++t2) {
        // wait for tile t2's 2 loads (2 younger tiles' 4 loads stay in flight)
        asm volatile("s_waitcnt vmcnt(4)" ::: "memory");
        __builtin_amdgcn_sched_barrier(0);
        __builtin_amdgcn_s_barrier();
        __builtin_amdgcn_sched_barrier(0);
        COMPUTE(buf);
        __builtin_amdgcn_s_barrier();            // all waves done reading buf
        __builtin_amdgcn_sched_barrier(0);
        STAGE(buf, (t2 + 3) * 32);
        __builtin_amdgcn_sched_barrier(0);
        buf = (buf == 2) ? 0 : buf + 1;
    }
    // tail: drain 3 remaining tiles, vmcnt 4 -> 2 -> 0
    asm volatile("s_waitcnt vmcnt(4)" ::: "memory");
    __builtin_amdgcn_sched_barrier(0);
    __builtin_amdgcn_s_barrier();
    __builtin_amdgcn_sched_barrier(0);
    COMPUTE(buf);
    buf = (buf == 2) ? 0 : buf + 1;
    asm volatile("s_waitcnt vmcnt(2)" ::: "memory");
    __builtin_amdgcn_sched_barrier(0);
    __builtin_amdgcn_s_barrier();
    __builtin_amdgcn_sched_barrier(0);
    COMPUTE(buf);
    buf = (buf == 2) ? 0 : buf + 1;
    asm volatile("s_waitcnt vmcnt(0)" ::: "memory");
    __builtin_amdgcn_sched_barrier(0);
    __builtin_amdgcn_s_barrier();
    __builtin_amdgcn_sched_barrier(0);
    COMPUTE(buf);

    const int rowW = row0 + wm * 32;
    const int colW = nb + wn * 64;
#pragma unroll
    for (int mi = 0; mi < 2; ++mi) {
#pragma unroll
        for (int nj = 0; nj < 4; ++nj) {
#pragma unroll
            for (int r = 0; r < 4; ++r) {
                int row = rowW + mi * 16 + (l >> 4) * 4 + r;
                int col = colW + nj * 16 + lr;
                if (row < rowEnd) {
                    float v = acc[mi][nj][r] + bias[e * ND + col];
                    if (FIRST)
                        ((bf16*)Out)[(size_t)row * ND + col] = (bf16)fmaxf(v, 0.f);
                    else
                        ((float*)Out)[(size_t)row * ND + col] = v;
                }
            }
        }
    }
}

// ---------------- combine: out[n] = w0*Y[slot0] + w1*Y[slot1] --------------------
__global__ __launch_bounds__(256)
void combine_kernel(const float* __restrict__ Yg, const int* __restrict__ pos,
                    const float* __restrict__ slot_w, float* __restrict__ out)
{
    int idx = blockIdx.x * 256 + threadIdx.x;  // over NTOK*DDIM/4
    int n = idx >> 7;                           // DDIM/4 = 128
    int d4 = idx & 127;
    int s0 = pos[n * 2 + 0], s1 = pos[n * 2 + 1];
    float w0 = slot_w[s0], w1 = slot_w[s1];
    float4 a = ((const float4*)(Yg + (size_t)s0 * DDIM))[d4];
    float4 b = ((const float4*)(Yg + (size_t)s1 * DDIM))[d4];
    float4 o;
    o.x = w0 * a.x + w1 * b.x;
    o.y = w0 * a.y + w1 * b.y;
    o.z = w0 * a.z + w1 * b.z;
    o.w = w0 * a.w + w1 * b.w;
    ((float4*)out)[idx] = o;
}

extern "C" void kernel_launch(void* const* d_in, const int* in_sizes, int n_in,
                              void* d_out, int out_size, void* d_ws, size_t ws_size,
                              hipStream_t stream)
{
    (void)in_sizes; (void)n_in;
    const float* x  = (const float*)d_in[0];
    const float* Wg = (const float*)d_in[1];
    const float* bg = (const float*)d_in[2];
    const float* W1 = (const float*)d_in[3];
    const float* b1 = (const float*)d_in[4];
    const float* W2 = (const float*)d_in[5];
    const float* b2 = (const float*)d_in[6];
    float* out = (float*)d_out;

    uint8_t* ws = (uint8_t*)d_ws;
    size_t off = 0;
    auto alloc = [&](size_t bytes) -> void* {
        void* p = ws + off;
        off = (off + bytes + 255) & ~(size_t)255;
        return p;
    };
    bf16*  xb      = (bf16*)alloc((size_t)NTOK * DDIM * 2);
    bf16*  w1t     = (bf16*)alloc((size_t)NEXP * FDIM * DDIM * 2);  // [E][FF][D]
    bf16*  w2t     = (bf16*)alloc((size_t)NEXP * DDIM * FDIM * 2);  // [E][D][FF]
    bf16*  Hg      = (bf16*)alloc((size_t)NSLOT * FDIM * 2);
    float* Yg      = (float*)alloc((size_t)NSLOT * DDIM * 4);
    int*   counts  = (int*)alloc(NEXP * 4);
    int*   cursors = (int*)alloc(NEXP * 4);
    int*   offsets = (int*)alloc((NEXP + 1) * 4);
    int*   ntiles  = (int*)alloc(4);
    int*   tmap_e  = (int*)alloc(MAXTILES * 4);
    int*   tmap_rt = (int*)alloc(MAXTILES * 4);
    int*   top_idx = (int*)alloc((size_t)NTOK * 2 * 4);
    float* top_w   = (float*)alloc((size_t)NTOK * 2 * 4);
    int*   pos     = (int*)alloc((size_t)NTOK * 2 * 4);
    int*   slot_tok= (int*)alloc((size_t)NSLOT * 4);
    float* slot_w  = (float*)alloc((size_t)NSLOT * 4);

    if (ws_size < off) {
        // workspace too small: distinguishable failure signature (out = 0)
        hipMemsetAsync(d_out, 0, (size_t)out_size * 4, stream);
        return;
    }

    hipMemsetAsync(counts, 0, NEXP * 4, stream);

    gating_kernel<<<1024, 256, 0, stream>>>(x, Wg, bg, xb, top_idx, top_w, counts);
    scan_kernel<<<1, 64, 0, stream>>>(counts, offsets, tmap_e, tmap_rt, ntiles, cursors);
    scatter_kernel<<<NTOK / 256, 256, 0, stream>>>(top_idx, top_w, offsets, cursors,
                                                   slot_tok, slot_w, pos);
    transpose_cvt<<<dim3(FDIM / 64, DDIM / 64, NEXP), 256, 0, stream>>>(W1, w1t, DDIM, FDIM);
    transpose_cvt<<<dim3(DDIM / 64, FDIM / 64, NEXP), 256, 0, stream>>>(W2, w2t, FDIM, DDIM);

    moe_gemm<DDIM, FDIM, true><<<dim3(FDIM / 128, MAXTILES), 512, 0, stream>>>(
        xb, w1t, b1, (void*)Hg, slot_tok, offsets, tmap_e, tmap_rt, ntiles);
    moe_gemm<FDIM, DDIM, false><<<dim3(DDIM / 128, MAXTILES), 512, 0, stream>>>(
        Hg, w2t, b2, (void*)Yg, slot_tok, offsets, tmap_e, tmap_rt, ntiles);

    combine_kernel<<<(NTOK * DDIM / 4) / 256, 256, 0, stream>>>(Yg, pos, slot_w, out);
}